// Round 5
// baseline (3993.962 us; speedup 1.0000x reference)
//
#include <hip/hip_runtime.h>
#include <math.h>

#define NB 256          // batch
#define XW 5048         // input row width
#define GENE 3000
#define DRUGW 2048
#define EPSF 1e-5f
#define NBLK 1024       // persistent grid: 4 blocks/CU (launch_bounds(256,4))
#define NSLOT 8         // barrier counter slots (cacheline-padded)

struct Params {
    const float* x;
    const int* cols0; const float* w0; const float* b0;
    const int* cols1; const float* w1; const float* b1;
    const float* w2;  const float* b2;
    const float* gg;  const float* eg;
    const float* g1;  const float* e1;
    const float* g2;  const float* e2;
    const float* Wd1; const float* bd1;
    const float* gd1; const float* ed1;
    const float* Wd2; const float* bd2;
    const float* gd2; const float* ed2;
    const float* Wd3; const float* bd3;
    const float* gd3; const float* ed3;
    const float* gf;  const float* ef;
    const float* Wf;  const float* bf;
    const float* ga;  const float* ea;
    const float* Wa;  const float* ba;
    const float* Wo;  const float* bo;
    float* out;
    float* gene_n; float* drug_n; float* h1i; float* h2i;
    float* fbn; float* d1n; float* d2n; float* o1n; float* part2; float* part1;
    unsigned int* bar;   // NSLOT padded counters (memset to 0 each call)
};

// ---------------------------------------------------------------------------
// Device-scope global barrier. Monotone counters in NSLOT cacheline-padded
// slots (avoids 1024-way same-address atomic serialization). target=phase*NBLK.
// All 1024 blocks co-resident: VGPR<=128 & LDS<=40KB -> 4 blocks/CU.
// ---------------------------------------------------------------------------
__device__ __forceinline__ void gbar(unsigned int* bar, unsigned int target) {
    __syncthreads();
    if (threadIdx.x == 0) {
        __threadfence();   // release this block's writes
        __hip_atomic_fetch_add(&bar[(blockIdx.x & (NSLOT - 1)) * 32], 1u,
                               __ATOMIC_RELEASE, __HIP_MEMORY_SCOPE_AGENT);
        unsigned int s;
        do {
            s = 0;
            #pragma unroll
            for (int i = 0; i < NSLOT; i++)
                s += __hip_atomic_load(&bar[i * 32], __ATOMIC_ACQUIRE,
                                       __HIP_MEMORY_SCOPE_AGENT);
            if (s < target) __builtin_amdgcn_s_sleep(4);
        } while (s < target);
        __threadfence();   // acquire side
    }
    __syncthreads();
}

// ---------------------------------------------------------------------------
// BN epilogue: thread b = batch index owns values v[NR] of rows r0..r0+NR-1.
// ---------------------------------------------------------------------------
template<int NR, bool ILEAVE>
__device__ __forceinline__ void bn_fold(float (&v)[NR], int b,
        const float* __restrict__ g, const float* __restrict__ e,
        float* __restrict__ out) {
    __shared__ float sred[NR][4][2];
    __shared__ float s_ac[2][NR];
    int lane = b & 63, wv = b >> 6;
    float s1[NR], s2[NR];
    #pragma unroll
    for (int k = 0; k < NR; k++) { s1[k] = v[k]; s2[k] = v[k] * v[k]; }
    #pragma unroll
    for (int off = 32; off >= 1; off >>= 1) {
        #pragma unroll
        for (int k = 0; k < NR; k++) {
            s1[k] += __shfl_xor(s1[k], off);
            s2[k] += __shfl_xor(s2[k], off);
        }
    }
    if (lane == 0) {
        #pragma unroll
        for (int k = 0; k < NR; k++) { sred[k][wv][0] = s1[k]; sred[k][wv][1] = s2[k]; }
    }
    __syncthreads();
    if (b < NR) {
        float t1 = sred[b][0][0] + sred[b][1][0] + sred[b][2][0] + sred[b][3][0];
        float t2 = sred[b][0][1] + sred[b][1][1] + sred[b][2][1] + sred[b][3][1];
        float mu  = t1 * (1.0f / 256.0f);
        float var = t2 * (1.0f / 256.0f) - mu * mu;
        float rs  = rsqrtf(var + EPSF);
        float aa  = g[b] * rs;
        s_ac[0][b] = aa;
        s_ac[1][b] = e[b] - aa * mu;
    }
    __syncthreads();
    #pragma unroll
    for (int k = 0; k < NR; k++) {
        float w = s_ac[0][k] * v[k] + s_ac[1][k];
        if (ILEAVE) out[b * NR + k] = w;
        else        out[k * NB + b] = w;
    }
}

// ---------------------------------------------------------------------------
// S0: input BN, 16-column tile (LDS ~20KB keeps 4 blocks/CU residency safe)
// ---------------------------------------------------------------------------
__device__ __forceinline__ void inbn_task(const Params& p, int task, int t,
        float* tile, float* red1, float* red2, float* s_a, float* s_c) {
    int tx = t & 15, ty = t >> 4;          // 16 cols x 16 row-groups
    int c0 = task * 16;
    int c = c0 + tx;
    bool valid = c < XW;
    float s1 = 0.f, s2 = 0.f;
    #pragma unroll 4
    for (int i = 0; i < 16; i++) {
        int r = ty * 16 + i;
        float v = valid ? p.x[(size_t)r * XW + c] : 0.f;
        tile[tx * 257 + r] = v;
        s1 += v; s2 += v * v;
    }
    red1[ty * 17 + tx] = s1; red2[ty * 17 + tx] = s2;
    __syncthreads();
    if (t < 16) {
        float t1 = 0.f, t2 = 0.f;
        #pragma unroll
        for (int k = 0; k < 16; k++) { t1 += red1[k * 17 + t]; t2 += red2[k * 17 + t]; }
        float mu  = t1 * (1.0f / 256.0f);
        float var = t2 * (1.0f / 256.0f) - mu * mu;
        float rs  = rsqrtf(var + EPSF);
        int col = c0 + t;
        float gv = 0.f, ev = 0.f;
        if (col < GENE)      { gv = p.gg[col];         ev = p.eg[col]; }
        else if (col < XW)   { gv = p.gd1[col - GENE]; ev = p.ed1[col - GENE]; }
        float aa = gv * rs;
        s_a[t] = aa; s_c[t] = ev - aa * mu;
    }
    __syncthreads();
    #pragma unroll 4
    for (int cc = 0; cc < 16; cc++) {
        int col = c0 + cc;
        if (col >= XW) break;
        float w = s_a[cc] * tile[cc * 257 + t] + s_c[cc];
        if (col < GENE) p.gene_n[(size_t)col * NB + t] = w;
        else            p.drug_n[(size_t)(col - GENE) * NB + t] = w;
    }
    __syncthreads();   // tile reused by next task
}

__device__ __forceinline__ void splin0_task(const Params& p, int t, int b) {
    float acc[6] = {0.f, 0.f, 0.f, 0.f, 0.f, 0.f};
    int base = t * 180;
    #pragma unroll
    for (int i = 0; i < 30; i++) {
        int ei = base + i * 6;
        int cc = p.cols0[ei];
        float v = p.gene_n[(size_t)cc * NB + b];
        #pragma unroll
        for (int k = 0; k < 6; k++) acc[k] += v * p.w0[ei + k];
    }
    float v6[6];
    #pragma unroll
    for (int k = 0; k < 6; k++) v6[k] = tanhf(acc[k] + p.b0[t * 6 + k]);
    // h1i interleaved: (t*256+b)*6+k
    bn_fold<6, true>(v6, b, p.g1 + t * 6, p.e1 + t * 6, p.h1i + (size_t)t * 6 * NB);
}

__device__ __forceinline__ void splin1_task(const Params& p, int o, int b) {
    float acc[6] = {0.f, 0.f, 0.f, 0.f, 0.f, 0.f};
    #pragma unroll
    for (int pi = 0; pi < 5; pi++) {
        int qb = (o * 5 + pi) * 36;
        int cbase = p.cols1[qb];                 // = child*6
        const float* hv = p.h1i + (size_t)cbase * NB + b * 6;
        const float2* hv2 = (const float2*)hv;   // 8B aligned
        float2 a0 = hv2[0], a1 = hv2[1], a2 = hv2[2];
        float v[6] = {a0.x, a0.y, a1.x, a1.y, a2.x, a2.y};
        #pragma unroll
        for (int j = 0; j < 6; j++)
            #pragma unroll
            for (int i = 0; i < 6; i++) acc[i] += v[j] * p.w1[qb + i * 6 + j];
    }
    float v6[6];
    #pragma unroll
    for (int i = 0; i < 6; i++) v6[i] = tanhf(acc[i] + p.b1[o * 6 + i]);
    bn_fold<6, true>(v6, b, p.g2 + o * 6, p.e2 + o * 6, p.h2i + (size_t)o * 6 * NB);
}

// splin2: dense 24x2400; 16 tasks, each computes ALL 24 kf over 25 terms
__device__ __forceinline__ void splin2_part_task(const Params& p, int ch, int b) {
    float acc[24];
    #pragma unroll
    for (int kf = 0; kf < 24; kf++) acc[kf] = 0.f;
    int t0 = ch * 25;
    for (int t = t0; t < t0 + 25; t++) {
        const float* hv = p.h2i + (size_t)t * 6 * NB + b * 6;
        const float2* hv2 = (const float2*)hv;
        float2 a0 = hv2[0], a1 = hv2[1], a2 = hv2[2];
        float v[6] = {a0.x, a0.y, a1.x, a1.y, a2.x, a2.y};
        const float* wr = p.w2 + t * 144;
        #pragma unroll
        for (int kf = 0; kf < 24; kf++)
            #pragma unroll
            for (int j = 0; j < 6; j++) acc[kf] += v[j] * wr[kf * 6 + j];
    }
    #pragma unroll
    for (int kf = 0; kf < 24; kf++)
        p.part2[(size_t)(ch * 24 + kf) * NB + b] = acc[kf];
}

__device__ __forceinline__ void splin2_fin_task(const Params& p, int kf, int b) {
    float acc = p.b2[kf];
    #pragma unroll
    for (int ch = 0; ch < 16; ch++) acc += p.part2[(size_t)(ch * 24 + kf) * NB + b];
    float v[1] = { tanhf(acc) };
    bn_fold<1, false>(v, b, p.gf + kf, p.ef + kf, p.fbn + (size_t)kf * NB);
}

__device__ __forceinline__ void dense1_part_task(const Params& p, int sub, int b) {
    int jg = sub >> 3, ch = sub & 7;
    int j0 = jg * 4, c0 = ch * 256;
    float acc[4] = {0.f, 0.f, 0.f, 0.f};
    for (int c = c0; c < c0 + 256; c++) {
        float v = p.drug_n[(size_t)c * NB + b];
        #pragma unroll
        for (int jj = 0; jj < 4; jj++) acc[jj] += v * p.Wd1[(size_t)(j0 + jj) * DRUGW + c];
    }
    #pragma unroll
    for (int jj = 0; jj < 4; jj++)
        p.part1[(size_t)((j0 + jj) * 8 + ch) * NB + b] = acc[jj];
}

__device__ __forceinline__ void dense1_fin_task(const Params& p, int j, int b) {
    float acc = p.bd1[j];
    #pragma unroll
    for (int ch = 0; ch < 8; ch++) acc += p.part1[(size_t)(j * 8 + ch) * NB + b];
    float v[1] = { tanhf(acc) };
    bn_fold<1, false>(v, b, p.gd2 + j, p.ed2 + j, p.d1n + (size_t)j * NB);
}

__device__ __forceinline__ void dense8_task(const float* __restrict__ in_n,
        const float* __restrict__ W, const float* __restrict__ bias, int ncols,
        const float* __restrict__ g, const float* __restrict__ e,
        float* __restrict__ out_n, int j0, int b) {
    float acc[8] = {0.f,0.f,0.f,0.f,0.f,0.f,0.f,0.f};
    for (int c = 0; c < ncols; c++) {
        float v = in_n[(size_t)c * NB + b];
        #pragma unroll
        for (int jj = 0; jj < 8; jj++) acc[jj] += v * W[(size_t)(j0 + jj) * ncols + c];
    }
    float v[8];
    #pragma unroll
    for (int jj = 0; jj < 8; jj++) v[jj] = tanhf(acc[jj] + bias[j0 + jj]);
    bn_fold<8, false>(v, b, g + j0, e + j0, out_n + (size_t)j0 * NB);
}

__device__ __forceinline__ void final_task(const Params& p, int b) {
    float acc = p.ba[0];
    #pragma unroll
    for (int j = 0; j < 64; j++) acc += p.o1n[(size_t)j * NB + b] * p.Wa[j];
    p.out[b] = tanhf(acc) * p.Wo[0] + p.bo[0];
}

// ---------------------------------------------------------------------------
// Persistent mega kernel: 7 stages, 6 software grid barriers.
// launch_bounds(256,4): 4 waves/EU -> VGPR<=128 -> 4 blocks/CU -> 1024 resident.
// ---------------------------------------------------------------------------
__global__ __launch_bounds__(256, 4) void k_mega(Params p) {
    __shared__ float tile[16 * 257];
    __shared__ float red1[16 * 17];
    __shared__ float red2[16 * 17];
    __shared__ float s_a[16], s_c[16];
    const int b = threadIdx.x;

    // S0: input BN + transpose (316 tasks of 16 cols)
    for (int task = blockIdx.x; task < 316; task += gridDim.x)
        inbn_task(p, task, b, tile, red1, red2, s_a, s_c);
    gbar(p.bar, 1 * NBLK);

    // S1: splin0 (1500) || dense1_part (256)
    for (int task = blockIdx.x; task < 1756; task += gridDim.x) {
        if (task < 1500) splin0_task(p, task, b);
        else             dense1_part_task(p, task - 1500, b);
    }
    gbar(p.bar, 2 * NBLK);

    // S2: splin1 (400) || dense1_fin (128)
    for (int task = blockIdx.x; task < 528; task += gridDim.x) {
        if (task < 400) splin1_task(p, task, b);
        else            dense1_fin_task(p, task - 400, b);
    }
    gbar(p.bar, 3 * NBLK);

    // S3: splin2_part (16) || dense2 (8)
    for (int task = blockIdx.x; task < 24; task += gridDim.x) {
        if (task < 16) splin2_part_task(p, task, b);
        else dense8_task(p.d1n, p.Wd2, p.bd2, 128, p.gd3, p.ed3, p.d2n, (task - 16) * 8, b);
    }
    gbar(p.bar, 4 * NBLK);

    // S4: splin2_fin (24) || dense3 (4)
    for (int task = blockIdx.x; task < 28; task += gridDim.x) {
        if (task < 24) splin2_fin_task(p, task, b);
        else dense8_task(p.d2n, p.Wd3, p.bd3, 64, p.gf + 24, p.ef + 24,
                         p.fbn + 24 * NB, (task - 24) * 8, b);
    }
    gbar(p.bar, 5 * NBLK);

    // S5: densef (8)
    for (int task = blockIdx.x; task < 8; task += gridDim.x)
        dense8_task(p.fbn, p.Wf, p.bf, 56, p.ga, p.ea, p.o1n, task * 8, b);
    gbar(p.bar, 6 * NBLK);

    // S6: final head (1)
    if (blockIdx.x == 0)
        final_task(p, b);
}

extern "C" void kernel_launch(void* const* d_in, const int* in_sizes, int n_in,
                              void* d_out, int out_size, void* d_ws, size_t ws_size,
                              hipStream_t stream) {
    Params p;
    p.x    = (const float*)d_in[0];
    p.cols0 = (const int*)d_in[2];
    p.w0   = (const float*)d_in[3];
    p.b0   = (const float*)d_in[4];
    p.cols1 = (const int*)d_in[6];
    p.w1   = (const float*)d_in[7];
    p.b1   = (const float*)d_in[8];
    p.w2   = (const float*)d_in[11];
    p.b2   = (const float*)d_in[12];
    p.gg   = (const float*)d_in[13];
    p.eg   = (const float*)d_in[14];
    p.g1   = (const float*)d_in[15];
    p.e1   = (const float*)d_in[16];
    p.g2   = (const float*)d_in[17];
    p.e2   = (const float*)d_in[18];
    p.Wd1  = (const float*)d_in[19];
    p.bd1  = (const float*)d_in[20];
    p.gd1  = (const float*)d_in[21];
    p.ed1  = (const float*)d_in[22];
    p.Wd2  = (const float*)d_in[23];
    p.bd2  = (const float*)d_in[24];
    p.gd2  = (const float*)d_in[25];
    p.ed2  = (const float*)d_in[26];
    p.Wd3  = (const float*)d_in[27];
    p.bd3  = (const float*)d_in[28];
    p.gd3  = (const float*)d_in[29];
    p.ed3  = (const float*)d_in[30];
    p.gf   = (const float*)d_in[31];
    p.ef   = (const float*)d_in[32];
    p.Wf   = (const float*)d_in[33];
    p.bf   = (const float*)d_in[34];
    p.ga   = (const float*)d_in[35];
    p.ea   = (const float*)d_in[36];
    p.Wa   = (const float*)d_in[37];
    p.ba   = (const float*)d_in[38];
    p.Wo   = (const float*)d_in[39];
    p.bo   = (const float*)d_in[40];
    p.out  = (float*)d_out;

    float* W = (float*)d_ws;
    p.gene_n = W;                         // 3000*256
    p.drug_n = p.gene_n + 3000 * NB;      // 2048*256
    p.h1i    = p.drug_n + 2048 * NB;      // 1500*6*256 (interleaved by 6)
    p.h2i    = p.h1i    + 9000 * NB;      // 400*6*256  (interleaved by 6)
    p.fbn    = p.h2i    + 2400 * NB;      // 56*256
    p.d1n    = p.fbn    + 56 * NB;        // 128*256
    p.d2n    = p.d1n    + 128 * NB;       // 64*256
    p.o1n    = p.d2n    + 64 * NB;        // 64*256
    p.part2  = p.o1n    + 64 * NB;        // 16*24*256
    p.part1  = p.part2  + 16 * 24 * NB;   // 128*8*256
    p.bar    = (unsigned int*)(p.part1 + 128 * 8 * NB);

    // zero the barrier counter slots (graph-capturable async memset)
    hipMemsetAsync((void*)p.bar, 0, NSLOT * 32 * sizeof(unsigned int), stream);

    k_mega<<<dim3(NBLK), dim3(256), 0, stream>>>(p);
}

// Round 6
// 479.685 us; speedup vs baseline: 8.3262x; 8.3262x over previous
//
#include <hip/hip_runtime.h>
#include <math.h>

#define NB 256          // batch
#define XW 5048         // input row width
#define GENE 3000
#define DRUGW 2048
#define EPSF 1e-5f
#define NBLK 1024       // persistent grid: 4 blocks/CU (launch_bounds(256,4))
#define NSLOT 8         // barrier counter slots (cacheline-padded)

// ---------------------------------------------------------------------------
// Cross-XCD coherent scalar access: agent-scope relaxed atomics compile to
// global_load/store with sc0 sc1 -> bypass per-XCD L2, hit the shared
// memory-side coherence point (L3). No fences needed anywhere.
// ---------------------------------------------------------------------------
__device__ __forceinline__ float ldc(const float* p) {
    return __hip_atomic_load(p, __ATOMIC_RELAXED, __HIP_MEMORY_SCOPE_AGENT);
}
__device__ __forceinline__ void stc(float* p, float v) {
    __hip_atomic_store(p, v, __ATOMIC_RELAXED, __HIP_MEMORY_SCOPE_AGENT);
}

struct Params {
    const float* x;
    const int* cols0; const float* w0; const float* b0;
    const int* cols1; const float* w1; const float* b1;
    const float* w2;  const float* b2;
    const float* gg;  const float* eg;
    const float* g1;  const float* e1;
    const float* g2;  const float* e2;
    const float* Wd1; const float* bd1;
    const float* gd1; const float* ed1;
    const float* Wd2; const float* bd2;
    const float* gd2; const float* ed2;
    const float* Wd3; const float* bd3;
    const float* gd3; const float* ed3;
    const float* gf;  const float* ef;
    const float* Wf;  const float* bf;
    const float* ga;  const float* ea;
    const float* Wa;  const float* ba;
    const float* Wo;  const float* bo;
    float* out;
    float* gene_n; float* drug_n; float* h1n; float* h2n;
    float* fbn; float* d1n; float* d2n; float* o1n; float* part2; float* part1;
    unsigned int* bar;   // NSLOT padded counters (memset to 0 each call)
};

// ---------------------------------------------------------------------------
// Global barrier WITHOUT cache fences. __syncthreads drains each wave's
// vmcnt (coherent stores reach the coherence point before the add). Spin is
// RELAXED (no buffer_inv); data visibility comes from coherent data accesses,
// not from the barrier.
// ---------------------------------------------------------------------------
__device__ __forceinline__ void gbar(unsigned int* bar, unsigned int target) {
    __syncthreads();
    if (threadIdx.x == 0) {
        __hip_atomic_fetch_add(&bar[(blockIdx.x & (NSLOT - 1)) * 32], 1u,
                               __ATOMIC_RELEASE, __HIP_MEMORY_SCOPE_AGENT);
        unsigned int s;
        do {
            s = 0;
            #pragma unroll
            for (int i = 0; i < NSLOT; i++)
                s += __hip_atomic_load(&bar[i * 32], __ATOMIC_RELAXED,
                                       __HIP_MEMORY_SCOPE_AGENT);
            if (s < target) __builtin_amdgcn_s_sleep(2);
        } while (s < target);
    }
    __syncthreads();
}

// ---------------------------------------------------------------------------
// BN epilogue: thread b = batch index owns values v[NR] of rows r0..r0+NR-1.
// Writes normalized rows feature-major via coherent stores.
// ---------------------------------------------------------------------------
template<int NR>
__device__ __forceinline__ void bn_fold(float (&v)[NR], int b,
        const float* __restrict__ g, const float* __restrict__ e,
        float* __restrict__ out) {
    __shared__ float sred[NR][4][2];
    __shared__ float s_ac[2][NR];
    int lane = b & 63, wv = b >> 6;
    float s1[NR], s2[NR];
    #pragma unroll
    for (int k = 0; k < NR; k++) { s1[k] = v[k]; s2[k] = v[k] * v[k]; }
    #pragma unroll
    for (int off = 32; off >= 1; off >>= 1) {
        #pragma unroll
        for (int k = 0; k < NR; k++) {
            s1[k] += __shfl_xor(s1[k], off);
            s2[k] += __shfl_xor(s2[k], off);
        }
    }
    if (lane == 0) {
        #pragma unroll
        for (int k = 0; k < NR; k++) { sred[k][wv][0] = s1[k]; sred[k][wv][1] = s2[k]; }
    }
    __syncthreads();
    if (b < NR) {
        float t1 = sred[b][0][0] + sred[b][1][0] + sred[b][2][0] + sred[b][3][0];
        float t2 = sred[b][0][1] + sred[b][1][1] + sred[b][2][1] + sred[b][3][1];
        float mu  = t1 * (1.0f / 256.0f);
        float var = t2 * (1.0f / 256.0f) - mu * mu;
        float rs  = rsqrtf(var + EPSF);
        float aa  = g[b] * rs;
        s_ac[0][b] = aa;
        s_ac[1][b] = e[b] - aa * mu;
    }
    __syncthreads();
    #pragma unroll
    for (int k = 0; k < NR; k++)
        stc(&out[(size_t)k * NB + b], s_ac[0][k] * v[k] + s_ac[1][k]);
}

// ---------------------------------------------------------------------------
// S0: input BN, 16-column tile, LDS transpose; coherent writes.
// ---------------------------------------------------------------------------
__device__ __forceinline__ void inbn_task(const Params& p, int task, int t,
        float* tile, float* red1, float* red2, float* s_a, float* s_c) {
    int tx = t & 15, ty = t >> 4;          // 16 cols x 16 row-groups
    int c0 = task * 16;
    int c = c0 + tx;
    bool valid = c < XW;
    float s1 = 0.f, s2 = 0.f;
    #pragma unroll 4
    for (int i = 0; i < 16; i++) {
        int r = ty * 16 + i;
        float v = valid ? p.x[(size_t)r * XW + c] : 0.f;
        tile[tx * 257 + r] = v;
        s1 += v; s2 += v * v;
    }
    red1[ty * 17 + tx] = s1; red2[ty * 17 + tx] = s2;
    __syncthreads();
    if (t < 16) {
        float t1 = 0.f, t2 = 0.f;
        #pragma unroll
        for (int k = 0; k < 16; k++) { t1 += red1[k * 17 + t]; t2 += red2[k * 17 + t]; }
        float mu  = t1 * (1.0f / 256.0f);
        float var = t2 * (1.0f / 256.0f) - mu * mu;
        float rs  = rsqrtf(var + EPSF);
        int col = c0 + t;
        float gv = 0.f, ev = 0.f;
        if (col < GENE)      { gv = p.gg[col];         ev = p.eg[col]; }
        else if (col < XW)   { gv = p.gd1[col - GENE]; ev = p.ed1[col - GENE]; }
        float aa = gv * rs;
        s_a[t] = aa; s_c[t] = ev - aa * mu;
    }
    __syncthreads();
    #pragma unroll 4
    for (int cc = 0; cc < 16; cc++) {
        int col = c0 + cc;
        if (col >= XW) break;
        float w = s_a[cc] * tile[cc * 257 + t] + s_c[cc];
        if (col < GENE) stc(&p.gene_n[(size_t)col * NB + t], w);
        else            stc(&p.drug_n[(size_t)(col - GENE) * NB + t], w);
    }
    __syncthreads();   // tile reused by next task
}

__device__ __forceinline__ void splin0_task(const Params& p, int t, int b) {
    float acc[6] = {0.f, 0.f, 0.f, 0.f, 0.f, 0.f};
    int base = t * 180;
    #pragma unroll
    for (int i = 0; i < 30; i++) {
        int ei = base + i * 6;
        int cc = p.cols0[ei];
        float v = ldc(&p.gene_n[(size_t)cc * NB + b]);
        #pragma unroll
        for (int k = 0; k < 6; k++) acc[k] += v * p.w0[ei + k];
    }
    float v6[6];
    #pragma unroll
    for (int k = 0; k < 6; k++) v6[k] = tanhf(acc[k] + p.b0[t * 6 + k]);
    bn_fold<6>(v6, b, p.g1 + t * 6, p.e1 + t * 6, p.h1n + (size_t)t * 6 * NB);
}

__device__ __forceinline__ void splin1_task(const Params& p, int o, int b) {
    float acc[6] = {0.f, 0.f, 0.f, 0.f, 0.f, 0.f};
    #pragma unroll
    for (int pi = 0; pi < 5; pi++) {
        int qb = (o * 5 + pi) * 36;
        int cbase = p.cols1[qb];                 // = child*6
        float v[6];
        #pragma unroll
        for (int j = 0; j < 6; j++)
            v[j] = ldc(&p.h1n[(size_t)(cbase + j) * NB + b]);
        #pragma unroll
        for (int j = 0; j < 6; j++)
            #pragma unroll
            for (int i = 0; i < 6; i++) acc[i] += v[j] * p.w1[qb + i * 6 + j];
    }
    float v6[6];
    #pragma unroll
    for (int i = 0; i < 6; i++) v6[i] = tanhf(acc[i] + p.b1[o * 6 + i]);
    bn_fold<6>(v6, b, p.g2 + o * 6, p.e2 + o * 6, p.h2n + (size_t)o * 6 * NB);
}

// splin2: dense 24x2400; 16 tasks, each computes ALL 24 kf over 25 terms
__device__ __forceinline__ void splin2_part_task(const Params& p, int ch, int b) {
    float acc[24];
    #pragma unroll
    for (int kf = 0; kf < 24; kf++) acc[kf] = 0.f;
    int t0 = ch * 25;
    for (int t = t0; t < t0 + 25; t++) {
        float v[6];
        #pragma unroll
        for (int j = 0; j < 6; j++)
            v[j] = ldc(&p.h2n[(size_t)(t * 6 + j) * NB + b]);
        const float* wr = p.w2 + t * 144;
        #pragma unroll
        for (int kf = 0; kf < 24; kf++)
            #pragma unroll
            for (int j = 0; j < 6; j++) acc[kf] += v[j] * wr[kf * 6 + j];
    }
    #pragma unroll
    for (int kf = 0; kf < 24; kf++)
        stc(&p.part2[(size_t)(ch * 24 + kf) * NB + b], acc[kf]);
}

__device__ __forceinline__ void splin2_fin_task(const Params& p, int kf, int b) {
    float acc = p.b2[kf];
    #pragma unroll
    for (int ch = 0; ch < 16; ch++)
        acc += ldc(&p.part2[(size_t)(ch * 24 + kf) * NB + b]);
    float v[1] = { tanhf(acc) };
    bn_fold<1>(v, b, p.gf + kf, p.ef + kf, p.fbn + (size_t)kf * NB);
}

// dense1 (2048->128): 128 tasks = 16 output-groups(8) x 8 col-chunks(256)
__device__ __forceinline__ void dense1_part_task(const Params& p, int sub, int b) {
    int jg = sub >> 3, ch = sub & 7;
    int j0 = jg * 8, c0 = ch * 256;
    float acc[8] = {0.f,0.f,0.f,0.f,0.f,0.f,0.f,0.f};
    for (int c = c0; c < c0 + 256; c++) {
        float v = ldc(&p.drug_n[(size_t)c * NB + b]);
        #pragma unroll
        for (int jj = 0; jj < 8; jj++) acc[jj] += v * p.Wd1[(size_t)(j0 + jj) * DRUGW + c];
    }
    #pragma unroll
    for (int jj = 0; jj < 8; jj++)
        stc(&p.part1[(size_t)((j0 + jj) * 8 + ch) * NB + b], acc[jj]);
}

__device__ __forceinline__ void dense1_fin_task(const Params& p, int j, int b) {
    float acc = p.bd1[j];
    #pragma unroll
    for (int ch = 0; ch < 8; ch++)
        acc += ldc(&p.part1[(size_t)(j * 8 + ch) * NB + b]);
    float v[1] = { tanhf(acc) };
    bn_fold<1>(v, b, p.gd2 + j, p.ed2 + j, p.d1n + (size_t)j * NB);
}

__device__ __forceinline__ void dense8_task(const float* __restrict__ in_n,
        const float* __restrict__ W, const float* __restrict__ bias, int ncols,
        const float* __restrict__ g, const float* __restrict__ e,
        float* __restrict__ out_n, int j0, int b) {
    float acc[8] = {0.f,0.f,0.f,0.f,0.f,0.f,0.f,0.f};
    for (int c = 0; c < ncols; c++) {
        float v = ldc(&in_n[(size_t)c * NB + b]);
        #pragma unroll
        for (int jj = 0; jj < 8; jj++) acc[jj] += v * W[(size_t)(j0 + jj) * ncols + c];
    }
    float v[8];
    #pragma unroll
    for (int jj = 0; jj < 8; jj++) v[jj] = tanhf(acc[jj] + bias[j0 + jj]);
    bn_fold<8>(v, b, g + j0, e + j0, out_n + (size_t)j0 * NB);
}

__device__ __forceinline__ void final_task(const Params& p, int b) {
    float acc = p.ba[0];
    #pragma unroll
    for (int j = 0; j < 64; j++)
        acc += ldc(&p.o1n[(size_t)j * NB + b]) * p.Wa[j];
    p.out[b] = tanhf(acc) * p.Wo[0] + p.bo[0];
}

// ---------------------------------------------------------------------------
// Persistent mega kernel: 7 stages, 6 fence-free global barriers.
// ---------------------------------------------------------------------------
__global__ __launch_bounds__(256, 4) void k_mega(Params p) {
    __shared__ float tile[16 * 257];
    __shared__ float red1[16 * 17];
    __shared__ float red2[16 * 17];
    __shared__ float s_a[16], s_c[16];
    const int b = threadIdx.x;

    // S0: input BN + transpose (316 tasks of 16 cols)
    for (int task = blockIdx.x; task < 316; task += gridDim.x)
        inbn_task(p, task, b, tile, red1, red2, s_a, s_c);
    gbar(p.bar, 1 * NBLK);

    // S1: splin0 (1500) || dense1_part (128)
    for (int task = blockIdx.x; task < 1628; task += gridDim.x) {
        if (task < 1500) splin0_task(p, task, b);
        else             dense1_part_task(p, task - 1500, b);
    }
    gbar(p.bar, 2 * NBLK);

    // S2: splin1 (400) || dense1_fin (128)
    for (int task = blockIdx.x; task < 528; task += gridDim.x) {
        if (task < 400) splin1_task(p, task, b);
        else            dense1_fin_task(p, task - 400, b);
    }
    gbar(p.bar, 3 * NBLK);

    // S3: splin2_part (16) || dense2 (8)
    for (int task = blockIdx.x; task < 24; task += gridDim.x) {
        if (task < 16) splin2_part_task(p, task, b);
        else dense8_task(p.d1n, p.Wd2, p.bd2, 128, p.gd3, p.ed3, p.d2n, (task - 16) * 8, b);
    }
    gbar(p.bar, 4 * NBLK);

    // S4: splin2_fin (24) || dense3 (4)
    for (int task = blockIdx.x; task < 28; task += gridDim.x) {
        if (task < 24) splin2_fin_task(p, task, b);
        else dense8_task(p.d2n, p.Wd3, p.bd3, 64, p.gf + 24, p.ef + 24,
                         p.fbn + 24 * NB, (task - 24) * 8, b);
    }
    gbar(p.bar, 5 * NBLK);

    // S5: densef (8)
    for (int task = blockIdx.x; task < 8; task += gridDim.x)
        dense8_task(p.fbn, p.Wf, p.bf, 56, p.ga, p.ea, p.o1n, task * 8, b);
    gbar(p.bar, 6 * NBLK);

    // S6: final head (1)
    if (blockIdx.x == 0)
        final_task(p, b);
}

extern "C" void kernel_launch(void* const* d_in, const int* in_sizes, int n_in,
                              void* d_out, int out_size, void* d_ws, size_t ws_size,
                              hipStream_t stream) {
    Params p;
    p.x    = (const float*)d_in[0];
    p.cols0 = (const int*)d_in[2];
    p.w0   = (const float*)d_in[3];
    p.b0   = (const float*)d_in[4];
    p.cols1 = (const int*)d_in[6];
    p.w1   = (const float*)d_in[7];
    p.b1   = (const float*)d_in[8];
    p.w2   = (const float*)d_in[11];
    p.b2   = (const float*)d_in[12];
    p.gg   = (const float*)d_in[13];
    p.eg   = (const float*)d_in[14];
    p.g1   = (const float*)d_in[15];
    p.e1   = (const float*)d_in[16];
    p.g2   = (const float*)d_in[17];
    p.e2   = (const float*)d_in[18];
    p.Wd1  = (const float*)d_in[19];
    p.bd1  = (const float*)d_in[20];
    p.gd1  = (const float*)d_in[21];
    p.ed1  = (const float*)d_in[22];
    p.Wd2  = (const float*)d_in[23];
    p.bd2  = (const float*)d_in[24];
    p.gd2  = (const float*)d_in[25];
    p.ed2  = (const float*)d_in[26];
    p.Wd3  = (const float*)d_in[27];
    p.bd3  = (const float*)d_in[28];
    p.gd3  = (const float*)d_in[29];
    p.ed3  = (const float*)d_in[30];
    p.gf   = (const float*)d_in[31];
    p.ef   = (const float*)d_in[32];
    p.Wf   = (const float*)d_in[33];
    p.bf   = (const float*)d_in[34];
    p.ga   = (const float*)d_in[35];
    p.ea   = (const float*)d_in[36];
    p.Wa   = (const float*)d_in[37];
    p.ba   = (const float*)d_in[38];
    p.Wo   = (const float*)d_in[39];
    p.bo   = (const float*)d_in[40];
    p.out  = (float*)d_out;

    float* W = (float*)d_ws;
    p.gene_n = W;                         // 3000*256
    p.drug_n = p.gene_n + 3000 * NB;      // 2048*256
    p.h1n    = p.drug_n + 2048 * NB;      // 9000*256 (feature-major)
    p.h2n    = p.h1n    + 9000 * NB;      // 2400*256
    p.fbn    = p.h2n    + 2400 * NB;      // 56*256
    p.d1n    = p.fbn    + 56 * NB;        // 128*256
    p.d2n    = p.d1n    + 128 * NB;       // 64*256
    p.o1n    = p.d2n    + 64 * NB;        // 64*256
    p.part2  = p.o1n    + 64 * NB;        // 16*24*256
    p.part1  = p.part2  + 16 * 24 * NB;   // 128*8*256
    p.bar    = (unsigned int*)(p.part1 + 128 * 8 * NB);

    // zero the barrier counter slots (graph-capturable async memset)
    hipMemsetAsync((void*)p.bar, 0, NSLOT * 32 * sizeof(unsigned int), stream);

    k_mega<<<dim3(NBLK), dim3(256), 0, stream>>>(p);
}

// Round 7
// 310.232 us; speedup vs baseline: 12.8741x; 1.5462x over previous
//
#include <hip/hip_runtime.h>
#include <math.h>

#define NB 256          // batch
#define XW 5048         // input row width
#define GENE 3000
#define DRUGW 2048
#define EPSF 1e-5f

struct Params {
    const float* x;
    const int* cols0; const float* w0; const float* b0;
    const int* cols1; const float* w1; const float* b1;
    const float* w2;  const float* b2;
    const float* gg;  const float* eg;
    const float* g1;  const float* e1;
    const float* g2;  const float* e2;
    const float* Wd1; const float* bd1;
    const float* gd1; const float* ed1;
    const float* Wd2; const float* bd2;
    const float* gd2; const float* ed2;
    const float* Wd3; const float* bd3;
    const float* gd3; const float* ed3;
    const float* gf;  const float* ef;
    const float* Wf;  const float* bf;
    const float* ga;  const float* ea;
    const float* Wa;  const float* ba;
    const float* Wo;  const float* bo;
    float* out;
    float* gene_n; float* drug_n; float* h1n; float* h2n;
    float* fbt;     // 56-feature concat buffer, BATCH-major: fbt[b*56 + f]
    float* d1n; float* d2n;
};

// ---------------------------------------------------------------------------
// BN epilogue: thread b = batch index owns v[NR] for rows r0..r0+NR-1.
// Batch mean/var per row (wave shuffle + LDS), fold gamma/beta, store
// normalized at out[k*RS + b*BS]. RS/BS are compile-time-foldable.
// ---------------------------------------------------------------------------
template<int NR>
__device__ __forceinline__ void bn_fold(float (&v)[NR], int b,
        const float* __restrict__ g, const float* __restrict__ e,
        float* __restrict__ out, int RS, int BS) {
    __shared__ float sred[NR][4][2];
    __shared__ float s_ac[2][NR];
    int lane = b & 63, wv = b >> 6;
    float s1[NR], s2[NR];
    #pragma unroll
    for (int k = 0; k < NR; k++) { s1[k] = v[k]; s2[k] = v[k] * v[k]; }
    #pragma unroll
    for (int off = 32; off >= 1; off >>= 1) {
        #pragma unroll
        for (int k = 0; k < NR; k++) {
            s1[k] += __shfl_xor(s1[k], off);
            s2[k] += __shfl_xor(s2[k], off);
        }
    }
    if (lane == 0) {
        #pragma unroll
        for (int k = 0; k < NR; k++) { sred[k][wv][0] = s1[k]; sred[k][wv][1] = s2[k]; }
    }
    __syncthreads();
    if (b < NR) {
        float t1 = sred[b][0][0] + sred[b][1][0] + sred[b][2][0] + sred[b][3][0];
        float t2 = sred[b][0][1] + sred[b][1][1] + sred[b][2][1] + sred[b][3][1];
        float mu  = t1 * (1.0f / 256.0f);
        float var = t2 * (1.0f / 256.0f) - mu * mu;
        float rs  = rsqrtf(var + EPSF);
        float aa  = g[b] * rs;
        s_ac[0][b] = aa;
        s_ac[1][b] = e[b] - aa * mu;
    }
    __syncthreads();
    #pragma unroll
    for (int k = 0; k < NR; k++)
        out[k * RS + b * BS] = s_ac[0][k] * v[k] + s_ac[1][k];
}

// ---------------------------------------------------------------------------
// K0: input BN. 32-col tiles, coalesced read of x, LDS transpose, write
// normalized feature-major gene_n / drug_n. (proven in round 2)
// ---------------------------------------------------------------------------
__global__ void k_inbn(Params p) {
    __shared__ float tile[32 * 257];
    __shared__ float red1[8][33], red2[8][33];
    __shared__ float s_a[32], s_c[32];
    int t = threadIdx.x;
    int tx = t & 31, ty = t >> 5;
    int c0 = blockIdx.x * 32;
    int c = c0 + tx;
    bool valid = c < XW;
    float s1 = 0.f, s2 = 0.f;
    #pragma unroll 4
    for (int i = 0; i < 32; i++) {
        int r = ty * 32 + i;
        float v = valid ? p.x[(size_t)r * XW + c] : 0.f;
        tile[tx * 257 + r] = v;
        s1 += v; s2 += v * v;
    }
    red1[ty][tx] = s1; red2[ty][tx] = s2;
    __syncthreads();
    if (t < 32) {
        float t1 = 0.f, t2 = 0.f;
        #pragma unroll
        for (int k = 0; k < 8; k++) { t1 += red1[k][t]; t2 += red2[k][t]; }
        float mu  = t1 * (1.0f / 256.0f);
        float var = t2 * (1.0f / 256.0f) - mu * mu;
        float rs  = rsqrtf(var + EPSF);
        int col = c0 + t;
        float gv = 0.f, ev = 0.f;
        if (col < GENE)      { gv = p.gg[col];         ev = p.eg[col]; }
        else if (col < XW)   { gv = p.gd1[col - GENE]; ev = p.ed1[col - GENE]; }
        float aa = gv * rs;
        s_a[t] = aa; s_c[t] = ev - aa * mu;
    }
    __syncthreads();
    for (int cc = 0; cc < 32; cc++) {
        int col = c0 + cc;
        if (col >= XW) break;
        float w = s_a[cc] * tile[cc * 257 + t] + s_c[cc];
        if (col < GENE) p.gene_n[(size_t)col * NB + t] = w;
        else            p.drug_n[(size_t)(col - GENE) * NB + t] = w;
    }
}

// ---------------------------------------------------------------------------
// K1: splin0 (1500 tasks) || dense1 one-shot (64 tasks x 2 outputs)
// ---------------------------------------------------------------------------
__global__ void k_s1(Params p) {
    int task = blockIdx.x, b = threadIdx.x;
    if (task < 1500) {
        int t = task;
        float acc[6] = {0.f, 0.f, 0.f, 0.f, 0.f, 0.f};
        int base = t * 180;
        #pragma unroll 2
        for (int i = 0; i < 30; i++) {
            int ei = base + i * 6;
            int cc = p.cols0[ei];
            float v = p.gene_n[(size_t)cc * NB + b];
            #pragma unroll
            for (int k = 0; k < 6; k++) acc[k] += v * p.w0[ei + k];
        }
        float v6[6];
        #pragma unroll
        for (int k = 0; k < 6; k++) v6[k] = tanhf(acc[k] + p.b0[t * 6 + k]);
        bn_fold<6>(v6, b, p.g1 + t * 6, p.e1 + t * 6,
                   p.h1n + (size_t)t * 6 * NB, NB, 1);
    } else {
        int j0 = (task - 1500) * 2;              // 2 outputs, 2048 cols
        float acc[2] = {0.f, 0.f};
        const float* w0r = p.Wd1 + (size_t)j0 * DRUGW;
        const float* w1r = w0r + DRUGW;
        #pragma unroll 4
        for (int c = 0; c < DRUGW; c++) {
            float v = p.drug_n[(size_t)c * NB + b];
            acc[0] += v * w0r[c];
            acc[1] += v * w1r[c];
        }
        float v2[2];
        v2[0] = tanhf(acc[0] + p.bd1[j0]);
        v2[1] = tanhf(acc[1] + p.bd1[j0 + 1]);
        bn_fold<2>(v2, b, p.gd2 + j0, p.ed2 + j0,
                   p.d1n + (size_t)j0 * NB, NB, 1);
    }
}

// ---------------------------------------------------------------------------
// K2: splin1 (400 tasks) || dense2 (8 tasks x 8 outputs, 128 cols)
// ---------------------------------------------------------------------------
__global__ void k_s2(Params p) {
    int task = blockIdx.x, b = threadIdx.x;
    if (task < 400) {
        int o = task;
        float acc[6] = {0.f, 0.f, 0.f, 0.f, 0.f, 0.f};
        #pragma unroll
        for (int pi = 0; pi < 5; pi++) {
            int qb = (o * 5 + pi) * 36;
            int cbase = p.cols1[qb];             // = child*6
            float v[6];
            #pragma unroll
            for (int j = 0; j < 6; j++)
                v[j] = p.h1n[(size_t)(cbase + j) * NB + b];
            #pragma unroll
            for (int j = 0; j < 6; j++)
                #pragma unroll
                for (int i = 0; i < 6; i++) acc[i] += v[j] * p.w1[qb + i * 6 + j];
        }
        float v6[6];
        #pragma unroll
        for (int i = 0; i < 6; i++) v6[i] = tanhf(acc[i] + p.b1[o * 6 + i]);
        bn_fold<6>(v6, b, p.g2 + o * 6, p.e2 + o * 6,
                   p.h2n + (size_t)o * 6 * NB, NB, 1);
    } else {
        int j0 = (task - 400) * 8;               // dense2: 128 -> 64
        float acc[8] = {0.f,0.f,0.f,0.f,0.f,0.f,0.f,0.f};
        for (int c = 0; c < 128; c++) {
            float v = p.d1n[(size_t)c * NB + b];
            #pragma unroll
            for (int jj = 0; jj < 8; jj++)
                acc[jj] += v * p.Wd2[(size_t)(j0 + jj) * 128 + c];
        }
        float v8[8];
        #pragma unroll
        for (int jj = 0; jj < 8; jj++) v8[jj] = tanhf(acc[jj] + p.bd2[j0 + jj]);
        bn_fold<8>(v8, b, p.gd3 + j0, p.ed3 + j0,
                   p.d2n + (size_t)j0 * NB, NB, 1);
    }
}

// ---------------------------------------------------------------------------
// K3: splin2 one-shot (24 tasks: dense 1x2400 row) || dense3 (4 tasks x 8,
// 64 cols). Both store into fbt BATCH-major (fbt[b*56+f]) for the tail.
// ---------------------------------------------------------------------------
__global__ void k_s3(Params p) {
    int task = blockIdx.x, b = threadIdx.x;
    if (task < 24) {
        int kf = task;
        float acc = 0.f;
        const float* wr = p.w2 + kf * 6;          // w2[t*144 + kf*6 + j]
        #pragma unroll 4
        for (int t = 0; t < 400; t++) {
            const float* hv = p.h2n + (size_t)t * 6 * NB + b;
            const float* wt = wr + t * 144;
            #pragma unroll
            for (int j = 0; j < 6; j++)
                acc += hv[(size_t)j * NB] * wt[j];
        }
        float v1[1] = { tanhf(acc + p.b2[kf]) };
        bn_fold<1>(v1, b, p.gf + kf, p.ef + kf, p.fbt + kf, 1, 56);
    } else {
        int j0 = (task - 24) * 8;                // dense3: 64 -> 32
        float acc[8] = {0.f,0.f,0.f,0.f,0.f,0.f,0.f,0.f};
        for (int c = 0; c < 64; c++) {
            float v = p.d2n[(size_t)c * NB + b];
            #pragma unroll
            for (int jj = 0; jj < 8; jj++)
                acc[jj] += v * p.Wd3[(size_t)(j0 + jj) * 64 + c];
        }
        float v8[8];
        #pragma unroll
        for (int jj = 0; jj < 8; jj++) v8[jj] = tanhf(acc[jj] + p.bd3[j0 + jj]);
        // rows 24+j0 .. 24+j0+7, batch-major
        bn_fold<8>(v8, b, p.gf + 24 + j0, p.ef + 24 + j0,
                   p.fbt + 24 + j0, 1, 56);
    }
}

// ---------------------------------------------------------------------------
// K4 (1 block): o1 = tanh(fbt_row @ Wf.T + bf); BN(ga,ea) in-register;
// o2 = tanh(o1 @ Wa.T + ba); out = o2*Wo + bo.
// ---------------------------------------------------------------------------
__global__ void k_tail(Params p) {
    __shared__ float sred[64][4][2];
    __shared__ float s_ac[2][64];
    int b = threadIdx.x;
    int lane = b & 63, wv = b >> 6;

    // own concat row into registers (14 x float4, contiguous)
    float row[56];
    const float4* rp = (const float4*)(p.fbt + (size_t)b * 56);
    #pragma unroll
    for (int i = 0; i < 14; i++) {
        float4 q = rp[i];
        row[i * 4 + 0] = q.x; row[i * 4 + 1] = q.y;
        row[i * 4 + 2] = q.z; row[i * 4 + 3] = q.w;
    }

    // densef: 64 outputs x 56 cols (Wf rows via scalar loads)
    float v[64];
    #pragma unroll 2
    for (int j = 0; j < 64; j++) {
        float acc = p.bf[j];
        const float* wr = p.Wf + j * 56;
        #pragma unroll
        for (int c = 0; c < 56; c++) acc += row[c] * wr[c];
        v[j] = tanhf(acc);
    }

    // BN over batch for 64 rows (sequential per row to bound VGPR)
    #pragma unroll
    for (int k = 0; k < 64; k++) {
        float s1 = v[k], s2 = v[k] * v[k];
        #pragma unroll
        for (int off = 32; off >= 1; off >>= 1) {
            s1 += __shfl_xor(s1, off);
            s2 += __shfl_xor(s2, off);
        }
        if (lane == 0) { sred[k][wv][0] = s1; sred[k][wv][1] = s2; }
    }
    __syncthreads();
    if (b < 64) {
        float t1 = sred[b][0][0] + sred[b][1][0] + sred[b][2][0] + sred[b][3][0];
        float t2 = sred[b][0][1] + sred[b][1][1] + sred[b][2][1] + sred[b][3][1];
        float mu  = t1 * (1.0f / 256.0f);
        float var = t2 * (1.0f / 256.0f) - mu * mu;
        float rs  = rsqrtf(var + EPSF);
        float aa  = p.ga[b] * rs;
        s_ac[0][b] = aa;
        s_ac[1][b] = p.ea[b] - aa * mu;
    }
    __syncthreads();

    // head
    float acc = p.ba[0];
    #pragma unroll
    for (int j = 0; j < 64; j++)
        acc += (s_ac[0][j] * v[j] + s_ac[1][j]) * p.Wa[j];
    p.out[b] = tanhf(acc) * p.Wo[0] + p.bo[0];
}

extern "C" void kernel_launch(void* const* d_in, const int* in_sizes, int n_in,
                              void* d_out, int out_size, void* d_ws, size_t ws_size,
                              hipStream_t stream) {
    Params p;
    p.x    = (const float*)d_in[0];
    p.cols0 = (const int*)d_in[2];
    p.w0   = (const float*)d_in[3];
    p.b0   = (const float*)d_in[4];
    p.cols1 = (const int*)d_in[6];
    p.w1   = (const float*)d_in[7];
    p.b1   = (const float*)d_in[8];
    p.w2   = (const float*)d_in[11];
    p.b2   = (const float*)d_in[12];
    p.gg   = (const float*)d_in[13];
    p.eg   = (const float*)d_in[14];
    p.g1   = (const float*)d_in[15];
    p.e1   = (const float*)d_in[16];
    p.g2   = (const float*)d_in[17];
    p.e2   = (const float*)d_in[18];
    p.Wd1  = (const float*)d_in[19];
    p.bd1  = (const float*)d_in[20];
    p.gd1  = (const float*)d_in[21];
    p.ed1  = (const float*)d_in[22];
    p.Wd2  = (const float*)d_in[23];
    p.bd2  = (const float*)d_in[24];
    p.gd2  = (const float*)d_in[25];
    p.ed2  = (const float*)d_in[26];
    p.Wd3  = (const float*)d_in[27];
    p.bd3  = (const float*)d_in[28];
    p.gd3  = (const float*)d_in[29];
    p.ed3  = (const float*)d_in[30];
    p.gf   = (const float*)d_in[31];
    p.ef   = (const float*)d_in[32];
    p.Wf   = (const float*)d_in[33];
    p.bf   = (const float*)d_in[34];
    p.ga   = (const float*)d_in[35];
    p.ea   = (const float*)d_in[36];
    p.Wa   = (const float*)d_in[37];
    p.ba   = (const float*)d_in[38];
    p.Wo   = (const float*)d_in[39];
    p.bo   = (const float*)d_in[40];
    p.out  = (float*)d_out;

    float* W = (float*)d_ws;
    p.gene_n = W;                         // 3000*256
    p.drug_n = p.gene_n + 3000 * NB;      // 2048*256
    p.h1n    = p.drug_n + 2048 * NB;      // 9000*256 (feature-major)
    p.h2n    = p.h1n    + 9000 * NB;      // 2400*256
    p.fbt    = p.h2n    + 2400 * NB;      // 256*56  (batch-major concat)
    p.d1n    = p.fbt    + NB * 56;        // 128*256
    p.d2n    = p.d1n    + 128 * NB;       // 64*256

    k_inbn<<<158, 256, 0, stream>>>(p);                 // S0
    k_s1  <<<1500 + 64, 256, 0, stream>>>(p);           // splin0 || dense1
    k_s2  <<<400 + 8, 256, 0, stream>>>(p);             // splin1 || dense2
    k_s3  <<<24 + 4, 256, 0, stream>>>(p);              // splin2 || dense3
    k_tail<<<1, 256, 0, stream>>>(p);                   // densef + BN + head
}